// Round 5
// baseline (406.548 us; speedup 1.0000x reference)
//
#include <hip/hip_runtime.h>
#include <stdint.h>

// Workspace layout (~48.4 MB):
//   xh    @ 0      : [4096][1024] bf16 (8 MB)  x hi part (= K hi)
//   xl    @ 8 MB   : [4096][1024] bf16 (8 MB)  x lo part
//   Wh    @ 16 MB  : [2048][1024] bf16 (4 MB)  W_qv^T hi
//   Wl    @ 20 MB  : [2048][1024] bf16 (4 MB)  W_qv^T lo
//   qwsf  @ 24 MB  : [8][16][512][64] f32 (16 MB) q full f32
//   vt    @ 40 MB  : [8][16][64][512] bf16 (8 MB) v transposed per head
//   poshi @ 48 MB          : [1088][64] bf16 (rows>=1024 zero)
//   poslo @ 48 MB + 192 KB : [1088][64] bf16
//
// Precision: logits match f32 reference via hi/lo bf16-split MFMA (~2^-18).
// k_attn is barrier-free: each wave owns 16 q-rows end-to-end; softmax fully
// in-register (shfl reductions); shift-band diagonal gathered via 2 shuffles
// + select (wave w needs only band tiles 3-w..7-w). LDS = P buffer only.

typedef __attribute__((ext_vector_type(8))) short s8v;
typedef __attribute__((ext_vector_type(4))) float f4v;

#define MFMA_BF16 __builtin_amdgcn_mfma_f32_16x16x32_bf16

__device__ __forceinline__ float bf2f(unsigned short s) {
  unsigned int u = ((unsigned int)s) << 16;
  float f;
  __builtin_memcpy(&f, &u, 4);
  return f;
}
__device__ __forceinline__ unsigned short f2bf(float f) {
  unsigned int u;
  __builtin_memcpy(&u, &f, 4);
  unsigned int r = (u + 0x7fffu + ((u >> 16) & 1u)) >> 16;
  return (unsigned short)r;
}
__device__ __forceinline__ bool is_bf16_in(const void* mask) {
  return (((const unsigned int*)mask)[0] & 0xFFFFu) != 0u;
}

// ---------------- split x -> xh, xl (bf16 hi/lo) ----------------
__global__ __launch_bounds__(256) void k_split_x(const void* __restrict__ X,
                                                 const void* __restrict__ mask,
                                                 unsigned short* __restrict__ xh,
                                                 unsigned short* __restrict__ xl) {
  const bool isb = is_bf16_in(mask);
  const int i = (blockIdx.x * 256 + threadIdx.x) * 8;
  s8v oh, ol;
  if (isb) {
    oh = *(const s8v*)((const unsigned short*)X + i);
#pragma unroll
    for (int j = 0; j < 8; ++j) ol[j] = 0;
  } else {
    const float* xf = (const float*)X + i;
#pragma unroll
    for (int j = 0; j < 8; ++j) {
      float v = xf[j];
      unsigned short hi = f2bf(v);
      oh[j] = (short)hi;
      ol[j] = (short)f2bf(v - bf2f(hi));
    }
  }
  *(s8v*)(xh + i) = oh;
  *(s8v*)(xl + i) = ol;
}

// ------- W transpose+split: W[1024][2048] -> Wh/Wl[2048][1024] bf16 -------
__global__ __launch_bounds__(256) void k_transpose(const void* __restrict__ W,
                                                   const void* __restrict__ mask,
                                                   unsigned short* __restrict__ Wh,
                                                   unsigned short* __restrict__ Wl) {
  __shared__ unsigned short th[64][65];
  __shared__ unsigned short tl[64][65];
  const bool isb = is_bf16_in(mask);
  const int n0 = blockIdx.x * 64;
  const int k0 = blockIdx.y * 64;
  const int t = threadIdx.x;
#pragma unroll
  for (int i = 0; i < 16; ++i) {
    int idx = t + i * 256;
    int kl = idx >> 6, nl = idx & 63;
    int src = (k0 + kl) * 2048 + n0 + nl;
    unsigned short hi, lo;
    if (isb) {
      hi = ((const unsigned short*)W)[src];
      lo = 0;
    } else {
      float v = ((const float*)W)[src];
      hi = f2bf(v);
      lo = f2bf(v - bf2f(hi));
    }
    th[nl][kl] = hi;
    tl[nl][kl] = lo;
  }
  __syncthreads();
#pragma unroll
  for (int i = 0; i < 16; ++i) {
    int idx = t + i * 256;
    int nl = idx >> 6, kl = idx & 63;
    Wh[(n0 + nl) * 1024 + k0 + kl] = th[nl][kl];
    Wl[(n0 + nl) * 1024 + k0 + kl] = tl[nl][kl];
  }
}

// ---------------- pos table: hi/lo split bf16, rows >= 1024 zeroed ----------------
__global__ __launch_bounds__(256) void k_pos(unsigned short* __restrict__ poshi,
                                             unsigned short* __restrict__ poslo) {
  int idx = blockIdx.x * 256 + threadIdx.x;
  if (idx >= 1088 * 64) return;
  int l = idx >> 6, i = idx & 63;
  unsigned short hi = 0, lo = 0;
  if (l < 1024) {
    int j = i & 31;
    float f = expf(-0.2971077539347156f * (float)j);  // -ln(10000)/31
    float ang = (float)(l - 512) * f;
    float v = (i < 32) ? sinf(ang) : cosf(ang);
    hi = f2bf(v);
    lo = f2bf(v - bf2f(hi));
  }
  poshi[idx] = hi;
  poslo[idx] = lo;
}

// ---- qv GEMM: ISQ=1 -> q cols (3-MFMA split, f32 out), ISQ=0 -> v cols ----
template <int ISQ>
__global__ __launch_bounds__(256, 2) void k_gemm(const unsigned short* __restrict__ xh,
                                                 const unsigned short* __restrict__ xl,
                                                 const unsigned short* __restrict__ Wh,
                                                 const unsigned short* __restrict__ Wl,
                                                 float* __restrict__ qwsf,
                                                 unsigned short* __restrict__ vt) {
  __shared__ unsigned short Ah[128 * 40];
  __shared__ unsigned short Bh[128 * 40];
  __shared__ unsigned short Al2[ISQ ? 128 * 40 : 64];
  __shared__ unsigned short Bl2[ISQ ? 128 * 40 : 64];
  const int m0 = blockIdx.y * 128;
  const int n0 = (ISQ ? 0 : 1024) + blockIdx.x * 128;
  const int t = threadIdx.x;
  const int w = t >> 6, lane = t & 63;
  const int wr = w >> 1, wc = w & 1;
  const int l16 = lane & 15, g = lane >> 4;

  const int ca = t, cb = t + 256;
  const int ra = ca >> 2, ka = ca & 3, rb = cb >> 2, kb = cb & 3;

  f4v acc[4][4];
#pragma unroll
  for (int i = 0; i < 4; ++i)
#pragma unroll
    for (int j = 0; j < 4; ++j) acc[i][j] = (f4v){0.f, 0.f, 0.f, 0.f};

  for (int k0 = 0; k0 < 1024; k0 += 32) {
    s8v xah = *(const s8v*)&xh[(m0 + ra) * 1024 + k0 + ka * 8];
    s8v xbh = *(const s8v*)&xh[(m0 + rb) * 1024 + k0 + kb * 8];
    s8v wha = *(const s8v*)&Wh[(n0 + ra) * 1024 + k0 + ka * 8];
    s8v whb = *(const s8v*)&Wh[(n0 + rb) * 1024 + k0 + kb * 8];
    s8v xal, xbl, wla, wlb;
    if (ISQ) {
      xal = *(const s8v*)&xl[(m0 + ra) * 1024 + k0 + ka * 8];
      xbl = *(const s8v*)&xl[(m0 + rb) * 1024 + k0 + kb * 8];
      wla = *(const s8v*)&Wl[(n0 + ra) * 1024 + k0 + ka * 8];
      wlb = *(const s8v*)&Wl[(n0 + rb) * 1024 + k0 + kb * 8];
    }
    __syncthreads();
    *(s8v*)&Ah[ra * 40 + ka * 8] = xah;
    *(s8v*)&Ah[rb * 40 + kb * 8] = xbh;
    *(s8v*)&Bh[ra * 40 + ka * 8] = wha;
    *(s8v*)&Bh[rb * 40 + kb * 8] = whb;
    if (ISQ) {
      *(s8v*)&Al2[ra * 40 + ka * 8] = xal;
      *(s8v*)&Al2[rb * 40 + kb * 8] = xbl;
      *(s8v*)&Bl2[ra * 40 + ka * 8] = wla;
      *(s8v*)&Bl2[rb * 40 + kb * 8] = wlb;
    }
    __syncthreads();
    s8v afh[4], bfh[4];
#pragma unroll
    for (int i = 0; i < 4; ++i) afh[i] = *(const s8v*)&Ah[(wr * 64 + i * 16 + l16) * 40 + g * 8];
#pragma unroll
    for (int j = 0; j < 4; ++j) bfh[j] = *(const s8v*)&Bh[(wc * 64 + j * 16 + l16) * 40 + g * 8];
    if (ISQ) {
      s8v afl[4], bfl[4];
#pragma unroll
      for (int i = 0; i < 4; ++i) afl[i] = *(const s8v*)&Al2[(wr * 64 + i * 16 + l16) * 40 + g * 8];
#pragma unroll
      for (int j = 0; j < 4; ++j) bfl[j] = *(const s8v*)&Bl2[(wc * 64 + j * 16 + l16) * 40 + g * 8];
#pragma unroll
      for (int i = 0; i < 4; ++i)
#pragma unroll
        for (int j = 0; j < 4; ++j) {
          acc[i][j] = MFMA_BF16(afh[i], bfh[j], acc[i][j], 0, 0, 0);
          acc[i][j] = MFMA_BF16(afl[i], bfh[j], acc[i][j], 0, 0, 0);
          acc[i][j] = MFMA_BF16(afh[i], bfl[j], acc[i][j], 0, 0, 0);
        }
    } else {
#pragma unroll
      for (int i = 0; i < 4; ++i)
#pragma unroll
        for (int j = 0; j < 4; ++j) acc[i][j] = MFMA_BF16(afh[i], bfh[j], acc[i][j], 0, 0, 0);
    }
  }

#pragma unroll
  for (int i = 0; i < 4; ++i) {
#pragma unroll
    for (int j = 0; j < 4; ++j) {
      int col = n0 + wc * 64 + j * 16 + l16;
#pragma unroll
      for (int jj = 0; jj < 4; ++jj) {
        int row = m0 + wr * 64 + i * 16 + g * 4 + jj;
        int bb = row >> 9, l = row & 511;
        if (ISQ) {
          int hh = col >> 6, d = col & 63;
          qwsf[((bb * 16 + hh) * 512 + l) * 64 + d] = acc[i][j][jj];
        } else {
          int c2 = col - 1024;
          int hh = c2 >> 6, d = c2 & 63;
          vt[((bb * 16 + hh) * 64 + d) * 512 + l] = f2bf(acc[i][j][jj]);
        }
      }
    }
  }
}

// ---------------- fused relative attention (barrier-free, per-wave) ----------------
// block (qt, bh): wave w owns q-rows [q0+16w, q0+16w+16). No __syncthreads.
__global__ __launch_bounds__(256, 3) void k_attn(const unsigned short* __restrict__ xh,
                                                 const unsigned short* __restrict__ xl,
                                                 const float* __restrict__ qwsf,
                                                 const unsigned short* __restrict__ vt,
                                                 const unsigned short* __restrict__ poshi,
                                                 const unsigned short* __restrict__ poslo,
                                                 const void* __restrict__ rrb,
                                                 const void* __restrict__ rwb,
                                                 const void* __restrict__ mask,
                                                 void* __restrict__ out) {
  __shared__ unsigned short P[4][16][68];  // per-wave P transpose buffer

  const bool isb = is_bf16_in(mask);
  const int qt = blockIdx.x;
  const int bh = blockIdx.y;
  const int b = bh >> 4, h = bh & 15;
  const int q0 = qt << 6;
  const int t = threadIdx.x;
  const int w = t >> 6;
  const int lane = t & 63;
  const int l16 = lane & 15;
  const int g = lane >> 4;

  // Q fragments, hi/lo split, both biases folded (BD = (q + r_w_bias) . pos)
  s8v qrh[2], qrl[2], qwh[2], qwl[2];
  {
    const int qrow = q0 + (w << 4) + l16;
    const float* qb = &qwsf[((b * 16 + h) * 512 + qrow) * 64];
#pragma unroll
    for (int f = 0; f < 2; ++f) {
      int d0 = f * 32 + g * 8;
#pragma unroll
      for (int j = 0; j < 8; ++j) {
        float qf = qb[d0 + j];
        float b1 = isb ? bf2f(((const unsigned short*)rrb)[h * 64 + d0 + j])
                       : ((const float*)rrb)[h * 64 + d0 + j];
        float b2 = isb ? bf2f(((const unsigned short*)rwb)[h * 64 + d0 + j])
                       : ((const float*)rwb)[h * 64 + d0 + j];
        float s1 = qf + b1, s2 = qf + b2;
        unsigned short h1 = f2bf(s1), h2 = f2bf(s2);
        qrh[f][j] = (short)h1;
        qrl[f][j] = (short)f2bf(s1 - bf2f(h1));
        qwh[f][j] = (short)h2;
        qwl[f][j] = (short)f2bf(s2 - bf2f(h2));
      }
    }
  }

  f4v accO[4];
#pragma unroll
  for (int d = 0; d < 4; ++d) accO[d] = (f4v){0.f, 0.f, 0.f, 0.f};
  float mrun[4] = {-3.0e38f, -3.0e38f, -3.0e38f, -3.0e38f};
  float lrun[4] = {0.f, 0.f, 0.f, 0.f};

  for (int kt = 0; kt < 8; ++kt) {
    const int k0 = kt << 6;
    const int l0t = k0 - q0 + 449;  // band col c: l = l0t + c; c = kk - qq + 63

    f4v a1[4], a2[5];
#pragma unroll
    for (int ct = 0; ct < 4; ++ct) a1[ct] = (f4v){0.f, 0.f, 0.f, 0.f};
#pragma unroll
    for (int i = 0; i < 5; ++i) a2[i] = (f4v){0.f, 0.f, 0.f, 0.f};

#pragma unroll
    for (int f = 0; f < 2; ++f) {
      const int dk = f * 32 + g * 8;
#pragma unroll
      for (int ct = 0; ct < 4; ++ct) {  // A1 = Qr . K^T (K = pre-split x)
        const int koff = (b * 512 + k0 + ct * 16 + l16) * 1024 + h * 64 + dk;
        s8v kh = *(const s8v*)&xh[koff];
        s8v klo = *(const s8v*)&xl[koff];
        a1[ct] = MFMA_BF16(qrh[f], kh, a1[ct], 0, 0, 0);
        a1[ct] = MFMA_BF16(qrl[f], kh, a1[ct], 0, 0, 0);
        a1[ct] = MFMA_BF16(qrh[f], klo, a1[ct], 0, 0, 0);
      }
#pragma unroll
      for (int i = 0; i < 5; ++i) {  // A2 band: wave w needs tiles 3-w..7-w only
        const int prow = l0t + (3 - w + i) * 16 + l16;
        s8v ph = *(const s8v*)&poshi[prow * 64 + dk];
        s8v pl = *(const s8v*)&poslo[prow * 64 + dk];
        a2[i] = MFMA_BF16(qwh[f], ph, a2[i], 0, 0, 0);
        a2[i] = MFMA_BF16(qwh[f], pl, a2[i], 0, 0, 0);
        a2[i] = MFMA_BF16(qwl[f], ph, a2[i], 0, 0, 0);
      }
    }

    // diagonal band gather via shuffle + mask + logits (all in registers)
    float mv[4];
#pragma unroll
    for (int ct = 0; ct < 4; ++ct) {
      int mi = b * 512 + k0 + ct * 16 + l16;
      mv[ct] = isb ? bf2f(((const unsigned short*)mask)[mi]) : ((const float*)mask)[mi];
    }
    float sv[4][4];
#pragma unroll
    for (int ct = 0; ct < 4; ++ct) {
#pragma unroll
      for (int jj = 0; jj < 4; ++jj) {
        // band[r][c], r = 4g+jj (local), c = ct*16+l16 - 16w - r + 63
        // source: lane (g, e&15), register a2[ct + (e>=64)][jj], e = l16-4g-jj+63
        int e = l16 - 4 * g - jj + 63;  // in [48, 78]
        int src = (lane & 48) | (e & 15);
        float v0 = __shfl(a2[ct][jj], src);
        float v1 = __shfl(a2[ct + 1 < 5 ? ct + 1 : 4][jj], src);
        float band = (e >= 64) ? v1 : v0;
        float s = a1[ct][jj] + band;
        s *= mv[ct];
        if (s == 0.f) s = -__builtin_inff();
        sv[ct][jj] = s;
      }
    }

    // in-register online softmax (rows 4g+jj live in 16-lane groups)
    float sc[4];
#pragma unroll
    for (int jj = 0; jj < 4; ++jj) {
      float pm = fmaxf(fmaxf(sv[0][jj], sv[1][jj]), fmaxf(sv[2][jj], sv[3][jj]));
      pm = fmaxf(pm, __shfl_xor(pm, 1));
      pm = fmaxf(pm, __shfl_xor(pm, 2));
      pm = fmaxf(pm, __shfl_xor(pm, 4));
      pm = fmaxf(pm, __shfl_xor(pm, 8));
      float mnew = fmaxf(mrun[jj], pm);
      float scale = __expf(mrun[jj] - mnew);
      float ps = 0.f;
#pragma unroll
      for (int ct = 0; ct < 4; ++ct) {
        float p = __expf(sv[ct][jj] - mnew);
        unsigned short pb = f2bf(p);
        P[w][4 * g + jj][ct * 16 + l16] = pb;
        ps += bf2f(pb);  // denominator consistent with bf16 numerator
      }
      ps += __shfl_xor(ps, 1);
      ps += __shfl_xor(ps, 2);
      ps += __shfl_xor(ps, 4);
      ps += __shfl_xor(ps, 8);
      lrun[jj] = lrun[jj] * scale + ps;
      mrun[jj] = mnew;
      sc[jj] = scale;
    }

    // O rescale + PV MFMA (intra-wave LDS dep; compiler inserts lgkmcnt)
#pragma unroll
    for (int d = 0; d < 4; ++d)
#pragma unroll
      for (int jj = 0; jj < 4; ++jj) accO[d][jj] *= sc[jj];
#pragma unroll
    for (int ks = 0; ks < 2; ++ks) {
      s8v pf = *(const s8v*)&P[w][l16][ks * 32 + g * 8];
#pragma unroll
      for (int d = 0; d < 4; ++d) {
        s8v vf = *(const s8v*)&vt[((b * 16 + h) * 64 + d * 16 + l16) * 512 + k0 + ks * 32 + g * 8];
        accO[d] = MFMA_BF16(pf, vf, accO[d], 0, 0, 0);
      }
    }
  }

  float inv[4];
#pragma unroll
  for (int jj = 0; jj < 4; ++jj) inv[jj] = 1.0f / lrun[jj];
#pragma unroll
  for (int d = 0; d < 4; ++d) {
#pragma unroll
    for (int jj = 0; jj < 4; ++jj) {
      int row = q0 + (w << 4) + 4 * g + jj;
      int idx = (b * 512 + row) * 1024 + h * 64 + d * 16 + l16;
      float val = accO[d][jj] * inv[jj];
      if (isb) ((unsigned short*)out)[idx] = f2bf(val);
      else ((float*)out)[idx] = val;
    }
  }
}

extern "C" void kernel_launch(void* const* d_in, const int* in_sizes, int n_in,
                              void* d_out, int out_size, void* d_ws, size_t ws_size,
                              hipStream_t stream) {
  (void)in_sizes; (void)n_in; (void)out_size; (void)ws_size;
  const void* x    = d_in[0];
  const void* mask = d_in[1];
  const void* wqv  = d_in[2];
  const void* rrb  = d_in[3];
  const void* rwb  = d_in[4];

  char* ws = (char*)d_ws;
  unsigned short* xh    = (unsigned short*)(ws);
  unsigned short* xl    = (unsigned short*)(ws + (8u << 20));
  unsigned short* Wh    = (unsigned short*)(ws + (16u << 20));
  unsigned short* Wl    = (unsigned short*)(ws + (20u << 20));
  float*          qwsf  = (float*)(ws + (24u << 20));
  unsigned short* vt    = (unsigned short*)(ws + (40u << 20));
  unsigned short* poshi = (unsigned short*)(ws + (48u << 20));
  unsigned short* poslo = (unsigned short*)(ws + (48u << 20) + (192u << 10));

  k_pos<<<dim3(272), 256, 0, stream>>>(poshi, poslo);
  k_transpose<<<dim3(32, 16), 256, 0, stream>>>(wqv, mask, Wh, Wl);
  k_split_x<<<dim3(2048), 256, 0, stream>>>(x, mask, xh, xl);
  k_gemm<1><<<dim3(8, 32), 256, 0, stream>>>(xh, xl, Wh, Wl, qwsf, vt);
  k_gemm<0><<<dim3(8, 32), 256, 0, stream>>>(xh, xl, Wh, Wl, qwsf, vt);
  k_attn<<<dim3(8, 128), 256, 0, stream>>>(xh, xl, qwsf, vt, poshi, poslo, rrb, rwb, mask, (void*)d_out);
}

// Round 6
// 218.643 us; speedup vs baseline: 1.8594x; 1.8594x over previous
//
#include <hip/hip_runtime.h>
#include <stdint.h>

// Workspace layout (~48.4 MB):
//   xh    @ 0      : [4096][1024] bf16 (8 MB)  x hi part (= K hi)
//   xl    @ 8 MB   : [4096][1024] bf16 (8 MB)  x lo part
//   Wh    @ 16 MB  : [2048][1024] bf16 (4 MB)  W_qv^T hi
//   Wl    @ 20 MB  : [2048][1024] bf16 (4 MB)  W_qv^T lo
//   qwsf  @ 24 MB  : [8][16][512][64] f32 (16 MB) q full f32
//   vt    @ 40 MB  : [8][16][64][512] bf16 (8 MB) v transposed per head
//   poshi @ 48 MB          : [1088][64] bf16 (rows>=1024 zero)
//   poslo @ 48 MB + 192 KB : [1088][64] bf16
//
// Precision: logits match f32 reference via hi/lo bf16-split MFMA (~2^-18).
// k_attn v3: block-level coalesced LDS staging of K/V/pos (round-5 showed the
// per-wave 16-line fragment gathers were the bottleneck: MfmaUtil 5%, all
// pipes idle). Pos band staged as a 128-row ring (64 new rows per k-tile).
// T14: next-tile loads issued to regs before compute, written to LDS after
// the barrier. Softmax/band-gather/PV math unchanged from the passing round.

typedef __attribute__((ext_vector_type(8))) short s8v;
typedef __attribute__((ext_vector_type(4))) float f4v;

#define MFMA_BF16 __builtin_amdgcn_mfma_f32_16x16x32_bf16

__device__ __forceinline__ float bf2f(unsigned short s) {
  unsigned int u = ((unsigned int)s) << 16;
  float f;
  __builtin_memcpy(&f, &u, 4);
  return f;
}
__device__ __forceinline__ unsigned short f2bf(float f) {
  unsigned int u;
  __builtin_memcpy(&u, &f, 4);
  unsigned int r = (u + 0x7fffu + ((u >> 16) & 1u)) >> 16;
  return (unsigned short)r;
}
__device__ __forceinline__ bool is_bf16_in(const void* mask) {
  return (((const unsigned int*)mask)[0] & 0xFFFFu) != 0u;
}

// ---------------- split x -> xh, xl (bf16 hi/lo) ----------------
__global__ __launch_bounds__(256) void k_split_x(const void* __restrict__ X,
                                                 const void* __restrict__ mask,
                                                 unsigned short* __restrict__ xh,
                                                 unsigned short* __restrict__ xl) {
  const bool isb = is_bf16_in(mask);
  const int i = (blockIdx.x * 256 + threadIdx.x) * 8;
  s8v oh, ol;
  if (isb) {
    oh = *(const s8v*)((const unsigned short*)X + i);
#pragma unroll
    for (int j = 0; j < 8; ++j) ol[j] = 0;
  } else {
    const float* xf = (const float*)X + i;
#pragma unroll
    for (int j = 0; j < 8; ++j) {
      float v = xf[j];
      unsigned short hi = f2bf(v);
      oh[j] = (short)hi;
      ol[j] = (short)f2bf(v - bf2f(hi));
    }
  }
  *(s8v*)(xh + i) = oh;
  *(s8v*)(xl + i) = ol;
}

// ------- W transpose+split: W[1024][2048] -> Wh/Wl[2048][1024] bf16 -------
__global__ __launch_bounds__(256) void k_transpose(const void* __restrict__ W,
                                                   const void* __restrict__ mask,
                                                   unsigned short* __restrict__ Wh,
                                                   unsigned short* __restrict__ Wl) {
  __shared__ unsigned short th[64][65];
  __shared__ unsigned short tl[64][65];
  const bool isb = is_bf16_in(mask);
  const int n0 = blockIdx.x * 64;
  const int k0 = blockIdx.y * 64;
  const int t = threadIdx.x;
#pragma unroll
  for (int i = 0; i < 16; ++i) {
    int idx = t + i * 256;
    int kl = idx >> 6, nl = idx & 63;
    int src = (k0 + kl) * 2048 + n0 + nl;
    unsigned short hi, lo;
    if (isb) {
      hi = ((const unsigned short*)W)[src];
      lo = 0;
    } else {
      float v = ((const float*)W)[src];
      hi = f2bf(v);
      lo = f2bf(v - bf2f(hi));
    }
    th[nl][kl] = hi;
    tl[nl][kl] = lo;
  }
  __syncthreads();
#pragma unroll
  for (int i = 0; i < 16; ++i) {
    int idx = t + i * 256;
    int nl = idx >> 6, kl = idx & 63;
    Wh[(n0 + nl) * 1024 + k0 + kl] = th[nl][kl];
    Wl[(n0 + nl) * 1024 + k0 + kl] = tl[nl][kl];
  }
}

// ---------------- pos table: hi/lo split bf16, rows >= 1024 zeroed ----------------
__global__ __launch_bounds__(256) void k_pos(unsigned short* __restrict__ poshi,
                                             unsigned short* __restrict__ poslo) {
  int idx = blockIdx.x * 256 + threadIdx.x;
  if (idx >= 1088 * 64) return;
  int l = idx >> 6, i = idx & 63;
  unsigned short hi = 0, lo = 0;
  if (l < 1024) {
    int j = i & 31;
    float f = expf(-0.2971077539347156f * (float)j);  // -ln(10000)/31
    float ang = (float)(l - 512) * f;
    float v = (i < 32) ? sinf(ang) : cosf(ang);
    hi = f2bf(v);
    lo = f2bf(v - bf2f(hi));
  }
  poshi[idx] = hi;
  poslo[idx] = lo;
}

// ---- qv GEMM (merged): x[4096][1024] x W[1024][2048] -> q (f32), v (bf16) ----
// blockIdx.x 0..7 -> q cols (3-MFMA split), 8..15 -> v cols (1 MFMA)
__global__ __launch_bounds__(256, 2) void k_gemm(const unsigned short* __restrict__ xh,
                                                 const unsigned short* __restrict__ xl,
                                                 const unsigned short* __restrict__ Wh,
                                                 const unsigned short* __restrict__ Wl,
                                                 float* __restrict__ qwsf,
                                                 unsigned short* __restrict__ vt) {
  __shared__ unsigned short Ah[128 * 40];
  __shared__ unsigned short Bh[128 * 40];
  __shared__ unsigned short Al2[128 * 40];
  __shared__ unsigned short Bl2[128 * 40];
  const int m0 = blockIdx.y * 128;
  const int n0 = blockIdx.x * 128;
  const bool isq = (n0 < 1024);
  const int t = threadIdx.x;
  const int w = t >> 6, lane = t & 63;
  const int wr = w >> 1, wc = w & 1;
  const int l16 = lane & 15, g = lane >> 4;

  const int ca = t, cb = t + 256;
  const int ra = ca >> 2, ka = ca & 3, rb = cb >> 2, kb = cb & 3;

  f4v acc[4][4];
#pragma unroll
  for (int i = 0; i < 4; ++i)
#pragma unroll
    for (int j = 0; j < 4; ++j) acc[i][j] = (f4v){0.f, 0.f, 0.f, 0.f};

  for (int k0 = 0; k0 < 1024; k0 += 32) {
    s8v xah = *(const s8v*)&xh[(m0 + ra) * 1024 + k0 + ka * 8];
    s8v xbh = *(const s8v*)&xh[(m0 + rb) * 1024 + k0 + kb * 8];
    s8v wha = *(const s8v*)&Wh[(n0 + ra) * 1024 + k0 + ka * 8];
    s8v whb = *(const s8v*)&Wh[(n0 + rb) * 1024 + k0 + kb * 8];
    s8v xal, xbl, wla, wlb;
    if (isq) {
      xal = *(const s8v*)&xl[(m0 + ra) * 1024 + k0 + ka * 8];
      xbl = *(const s8v*)&xl[(m0 + rb) * 1024 + k0 + kb * 8];
      wla = *(const s8v*)&Wl[(n0 + ra) * 1024 + k0 + ka * 8];
      wlb = *(const s8v*)&Wl[(n0 + rb) * 1024 + k0 + kb * 8];
    }
    __syncthreads();
    *(s8v*)&Ah[ra * 40 + ka * 8] = xah;
    *(s8v*)&Ah[rb * 40 + kb * 8] = xbh;
    *(s8v*)&Bh[ra * 40 + ka * 8] = wha;
    *(s8v*)&Bh[rb * 40 + kb * 8] = whb;
    if (isq) {
      *(s8v*)&Al2[ra * 40 + ka * 8] = xal;
      *(s8v*)&Al2[rb * 40 + kb * 8] = xbl;
      *(s8v*)&Bl2[ra * 40 + ka * 8] = wla;
      *(s8v*)&Bl2[rb * 40 + kb * 8] = wlb;
    }
    __syncthreads();
    s8v afh[4], bfh[4];
#pragma unroll
    for (int i = 0; i < 4; ++i) afh[i] = *(const s8v*)&Ah[(wr * 64 + i * 16 + l16) * 40 + g * 8];
#pragma unroll
    for (int j = 0; j < 4; ++j) bfh[j] = *(const s8v*)&Bh[(wc * 64 + j * 16 + l16) * 40 + g * 8];
    if (isq) {
      s8v afl[4], bfl[4];
#pragma unroll
      for (int i = 0; i < 4; ++i) afl[i] = *(const s8v*)&Al2[(wr * 64 + i * 16 + l16) * 40 + g * 8];
#pragma unroll
      for (int j = 0; j < 4; ++j) bfl[j] = *(const s8v*)&Bl2[(wc * 64 + j * 16 + l16) * 40 + g * 8];
#pragma unroll
      for (int i = 0; i < 4; ++i)
#pragma unroll
        for (int j = 0; j < 4; ++j) {
          acc[i][j] = MFMA_BF16(afh[i], bfh[j], acc[i][j], 0, 0, 0);
          acc[i][j] = MFMA_BF16(afl[i], bfh[j], acc[i][j], 0, 0, 0);
          acc[i][j] = MFMA_BF16(afh[i], bfl[j], acc[i][j], 0, 0, 0);
        }
    } else {
#pragma unroll
      for (int i = 0; i < 4; ++i)
#pragma unroll
        for (int j = 0; j < 4; ++j) acc[i][j] = MFMA_BF16(afh[i], bfh[j], acc[i][j], 0, 0, 0);
    }
  }

#pragma unroll
  for (int i = 0; i < 4; ++i) {
#pragma unroll
    for (int j = 0; j < 4; ++j) {
      int col = n0 + wc * 64 + j * 16 + l16;
#pragma unroll
      for (int jj = 0; jj < 4; ++jj) {
        int row = m0 + wr * 64 + i * 16 + g * 4 + jj;
        int bb = row >> 9, l = row & 511;
        if (isq) {
          int hh = col >> 6, d = col & 63;
          qwsf[((bb * 16 + hh) * 512 + l) * 64 + d] = acc[i][j][jj];
        } else {
          int c2 = col - 1024;
          int hh = c2 >> 6, d = c2 & 63;
          vt[((bb * 16 + hh) * 64 + d) * 512 + l] = f2bf(acc[i][j][jj]);
        }
      }
    }
  }
}

// ---------------- fused relative attention v3 (LDS-staged, T14) ----------------
// block (qt, bh), 256 thr; wave w owns q-rows [q0+16w, q0+16w+16).
__global__ __launch_bounds__(256, 2) void k_attn(const unsigned short* __restrict__ xh,
                                                 const unsigned short* __restrict__ xl,
                                                 const float* __restrict__ qwsf,
                                                 const unsigned short* __restrict__ vt,
                                                 const unsigned short* __restrict__ poshi,
                                                 const unsigned short* __restrict__ poslo,
                                                 const void* __restrict__ rrb,
                                                 const void* __restrict__ rwb,
                                                 const void* __restrict__ mask,
                                                 void* __restrict__ out) {
  __shared__ unsigned short Kh[64][72];
  __shared__ unsigned short Kl[64][72];
  __shared__ unsigned short Vv[64][72];   // rows = d, cols = k-local (from vt)
  __shared__ unsigned short Rh[128][72];  // pos ring hi, slot = abs_row & 127
  __shared__ unsigned short Rl[128][72];  // pos ring lo
  __shared__ unsigned short P[4][16][68];

  const bool isb = is_bf16_in(mask);
  const int qt = blockIdx.x;
  const int bh = blockIdx.y;
  const int b = bh >> 4, h = bh & 15;
  const int q0 = qt << 6;
  const int t = threadIdx.x;
  const int w = t >> 6;
  const int lane = t & 63;
  const int l16 = lane & 15;
  const int g = lane >> 4;
  const int bh64 = (b * 16 + h) * 64;

  // staging geometry: chunk = i*256 + t; row = chunk>>3; cc = (chunk&7)*8
  const int srow = t >> 3, scc = (t & 7) * 8;

  // ---- prologue: stage k-tile 0 (K, V) and pos window rows [l0t0, l0t0+127]
  {
    const int l0t0 = 449 - q0;
#pragma unroll
    for (int i = 0; i < 2; ++i) {
      int row = srow + i * 32;
      *(s8v*)&Kh[row][scc] = *(const s8v*)&xh[(b * 512 + row) * 1024 + h * 64 + scc];
      *(s8v*)&Kl[row][scc] = *(const s8v*)&xl[(b * 512 + row) * 1024 + h * 64 + scc];
      *(s8v*)&Vv[row][scc] = *(const s8v*)&vt[(bh64 + row) * 512 + scc];
    }
#pragma unroll
    for (int i = 0; i < 4; ++i) {
      int row = srow + i * 32;
      int a = l0t0 + row;
      *(s8v*)&Rh[a & 127][scc] = *(const s8v*)&poshi[a * 64 + scc];
      *(s8v*)&Rl[a & 127][scc] = *(const s8v*)&poslo[a * 64 + scc];
    }
  }

  // Q fragments, hi/lo split, both biases folded (BD = (q + r_w_bias) . pos)
  s8v qrh[2], qrl[2], qwh[2], qwl[2];
  {
    const int qrow = q0 + (w << 4) + l16;
    const float* qb = &qwsf[((b * 16 + h) * 512 + qrow) * 64];
#pragma unroll
    for (int f = 0; f < 2; ++f) {
      int d0 = f * 32 + g * 8;
#pragma unroll
      for (int j = 0; j < 8; ++j) {
        float qf = qb[d0 + j];
        float b1 = isb ? bf2f(((const unsigned short*)rrb)[h * 64 + d0 + j])
                       : ((const float*)rrb)[h * 64 + d0 + j];
        float b2 = isb ? bf2f(((const unsigned short*)rwb)[h * 64 + d0 + j])
                       : ((const float*)rwb)[h * 64 + d0 + j];
        float s1 = qf + b1, s2 = qf + b2;
        unsigned short h1 = f2bf(s1), h2 = f2bf(s2);
        qrh[f][j] = (short)h1;
        qrl[f][j] = (short)f2bf(s1 - bf2f(h1));
        qwh[f][j] = (short)h2;
        qwl[f][j] = (short)f2bf(s2 - bf2f(h2));
      }
    }
  }

  f4v accO[4];
#pragma unroll
  for (int d = 0; d < 4; ++d) accO[d] = (f4v){0.f, 0.f, 0.f, 0.f};
  float mrun[4] = {-3.0e38f, -3.0e38f, -3.0e38f, -3.0e38f};
  float lrun[4] = {0.f, 0.f, 0.f, 0.f};

  __syncthreads();

#pragma unroll 1
  for (int kt = 0; kt < 8; ++kt) {
    const int k0 = kt << 6;
    const int l0t = k0 - q0 + 449;

    // ---- T14: issue next tile's loads early (regs), write after barrier ----
    s8v nKh[2], nKl[2], nV[2], nPh[2], nPl[2];
    const bool hasNext = (kt < 7);
    if (hasNext) {
      const int k0n = k0 + 64;
#pragma unroll
      for (int i = 0; i < 2; ++i) {
        int row = srow + i * 32;
        nKh[i] = *(const s8v*)&xh[(b * 512 + k0n + row) * 1024 + h * 64 + scc];
        nKl[i] = *(const s8v*)&xl[(b * 512 + k0n + row) * 1024 + h * 64 + scc];
        nV[i] = *(const s8v*)&vt[(bh64 + row) * 512 + k0n + scc];
        int a = l0t + 128 + row;  // new 64 pos rows for next window
        nPh[i] = *(const s8v*)&poshi[a * 64 + scc];
        nPl[i] = *(const s8v*)&poslo[a * 64 + scc];
      }
    }

    // ---- compute current tile from LDS ----
    f4v a1[4], a2[5];
#pragma unroll
    for (int ct = 0; ct < 4; ++ct) a1[ct] = (f4v){0.f, 0.f, 0.f, 0.f};
#pragma unroll
    for (int i = 0; i < 5; ++i) a2[i] = (f4v){0.f, 0.f, 0.f, 0.f};

#pragma unroll
    for (int f = 0; f < 2; ++f) {
      const int dk = f * 32 + g * 8;
#pragma unroll
      for (int ct = 0; ct < 4; ++ct) {  // A1 = Qr . K^T
        s8v kh = *(const s8v*)&Kh[ct * 16 + l16][dk];
        s8v klo = *(const s8v*)&Kl[ct * 16 + l16][dk];
        a1[ct] = MFMA_BF16(qrh[f], kh, a1[ct], 0, 0, 0);
        a1[ct] = MFMA_BF16(qrl[f], kh, a1[ct], 0, 0, 0);
        a1[ct] = MFMA_BF16(qrh[f], klo, a1[ct], 0, 0, 0);
      }
#pragma unroll
      for (int i = 0; i < 5; ++i) {  // A2 band: wave w needs tiles 3-w..7-w
        const int slot = (l0t + (3 - w + i) * 16 + l16) & 127;
        s8v ph = *(const s8v*)&Rh[slot][dk];
        s8v pl = *(const s8v*)&Rl[slot][dk];
        a2[i] = MFMA_BF16(qwh[f], ph, a2[i], 0, 0, 0);
        a2[i] = MFMA_BF16(qwh[f], pl, a2[i], 0, 0, 0);
        a2[i] = MFMA_BF16(qwl[f], ph, a2[i], 0, 0, 0);
      }
    }

    // diagonal band gather via shuffle + mask + logits (registers only)
    float mv[4];
#pragma unroll
    for (int ct = 0; ct < 4; ++ct) {
      int mi = b * 512 + k0 + ct * 16 + l16;
      mv[ct] = isb ? bf2f(((const unsigned short*)mask)[mi]) : ((const float*)mask)[mi];
    }
    float sv[4][4];
#pragma unroll
    for (int ct = 0; ct < 4; ++ct) {
#pragma unroll
      for (int jj = 0; jj < 4; ++jj) {
        int e = l16 - 4 * g - jj + 63;  // in [48, 78]
        int src = (lane & 48) | (e & 15);
        float v0 = __shfl(a2[ct][jj], src);
        float v1 = __shfl(a2[ct + 1 < 5 ? ct + 1 : 4][jj], src);
        float band = (e >= 64) ? v1 : v0;
        float s = a1[ct][jj] + band;
        s *= mv[ct];
        if (s == 0.f) s = -__builtin_inff();
        sv[ct][jj] = s;
      }
    }

    // in-register online softmax (rows 4g+jj live in 16-lane groups)
    float sc[4];
#pragma unroll
    for (int jj = 0; jj < 4; ++jj) {
      float pm = fmaxf(fmaxf(sv[0][jj], sv[1][jj]), fmaxf(sv[2][jj], sv[3][jj]));
      pm = fmaxf(pm, __shfl_xor(pm, 1));
      pm = fmaxf(pm, __shfl_xor(pm, 2));
      pm = fmaxf(pm, __shfl_xor(pm, 4));
      pm = fmaxf(pm, __shfl_xor(pm, 8));
      float mnew = fmaxf(mrun[jj], pm);
      float scale = __expf(mrun[jj] - mnew);
      float ps = 0.f;
#pragma unroll
      for (int ct = 0; ct < 4; ++ct) {
        float p = __expf(sv[ct][jj] - mnew);
        unsigned short pb = f2bf(p);
        P[w][4 * g + jj][ct * 16 + l16] = pb;
        ps += bf2f(pb);
      }
      ps += __shfl_xor(ps, 1);
      ps += __shfl_xor(ps, 2);
      ps += __shfl_xor(ps, 4);
      ps += __shfl_xor(ps, 8);
      lrun[jj] = lrun[jj] * scale + ps;
      mrun[jj] = mnew;
      sc[jj] = scale;
    }

    // O rescale + PV MFMA (V from LDS)
#pragma unroll
    for (int d = 0; d < 4; ++d)
#pragma unroll
      for (int jj = 0; jj < 4; ++jj) accO[d][jj] *= sc[jj];
#pragma unroll
    for (int ks = 0; ks < 2; ++ks) {
      s8v pf = *(const s8v*)&P[w][l16][ks * 32 + g * 8];
#pragma unroll
      for (int d = 0; d < 4; ++d) {
        s8v vf = *(const s8v*)&Vv[d * 16 + l16][ks * 32 + g * 8];
        accO[d] = MFMA_BF16(pf, vf, accO[d], 0, 0, 0);
      }
    }

    __syncthreads();  // all waves done reading this tile
    if (hasNext) {
#pragma unroll
      for (int i = 0; i < 2; ++i) {
        int row = srow + i * 32;
        *(s8v*)&Kh[row][scc] = nKh[i];
        *(s8v*)&Kl[row][scc] = nKl[i];
        *(s8v*)&Vv[row][scc] = nV[i];
        int a = l0t + 128 + row;
        *(s8v*)&Rh[a & 127][scc] = nPh[i];
        *(s8v*)&Rl[a & 127][scc] = nPl[i];
      }
    }
    __syncthreads();
  }

  float inv[4];
#pragma unroll
  for (int jj = 0; jj < 4; ++jj) inv[jj] = 1.0f / lrun[jj];
#pragma unroll
  for (int d = 0; d < 4; ++d) {
#pragma unroll
    for (int jj = 0; jj < 4; ++jj) {
      int row = q0 + (w << 4) + 4 * g + jj;
      int idx = (b * 512 + row) * 1024 + h * 64 + d * 16 + l16;
      float val = accO[d][jj] * inv[jj];
      if (isb) ((unsigned short*)out)[idx] = f2bf(val);
      else ((float*)out)[idx] = val;
    }
  }
}

extern "C" void kernel_launch(void* const* d_in, const int* in_sizes, int n_in,
                              void* d_out, int out_size, void* d_ws, size_t ws_size,
                              hipStream_t stream) {
  (void)in_sizes; (void)n_in; (void)out_size; (void)ws_size;
  const void* x    = d_in[0];
  const void* mask = d_in[1];
  const void* wqv  = d_in[2];
  const void* rrb  = d_in[3];
  const void* rwb  = d_in[4];

  char* ws = (char*)d_ws;
  unsigned short* xh    = (unsigned short*)(ws);
  unsigned short* xl    = (unsigned short*)(ws + (8u << 20));
  unsigned short* Wh    = (unsigned short*)(ws + (16u << 20));
  unsigned short* Wl    = (unsigned short*)(ws + (20u << 20));
  float*          qwsf  = (float*)(ws + (24u << 20));
  unsigned short* vt    = (unsigned short*)(ws + (40u << 20));
  unsigned short* poshi = (unsigned short*)(ws + (48u << 20));
  unsigned short* poslo = (unsigned short*)(ws + (48u << 20) + (192u << 10));

  k_pos<<<dim3(272), 256, 0, stream>>>(poshi, poslo);
  k_transpose<<<dim3(32, 16), 256, 0, stream>>>(wqv, mask, Wh, Wl);
  k_split_x<<<dim3(2048), 256, 0, stream>>>(x, mask, xh, xl);
  k_gemm<<<dim3(16, 32), 256, 0, stream>>>(xh, xl, Wh, Wl, qwsf, vt);
  k_attn<<<dim3(8, 128), 256, 0, stream>>>(xh, xl, qwsf, vt, poshi, poslo, rrb, rwb, mask, (void*)d_out);
}